// Round 3
// baseline (2492.375 us; speedup 1.0000x reference)
//
#include <hip/hip_runtime.h>
#include <hip/hip_fp16.h>
#include <cmath>

#define Nn   100000
#define Ee   1600000
#define FIN  256
#define Hh   128
#define EDIMM 16
#define NL   3
#define NOUT 64

// ---------------- in_proj: h = x @ in_w + in_b  [N,256]@[256,128] ----------------
__global__ __launch_bounds__(128) void in_proj_kernel(const float* __restrict__ x,
    const float* __restrict__ w, const float* __restrict__ b, float* __restrict__ h) {
  __shared__ float xs[8][FIN];
  int r0 = blockIdx.x * 8;
  for (int i = threadIdx.x; i < 8 * FIN; i += 128) {
    int r = i >> 8, c = i & (FIN - 1);
    int rr = r0 + r;
    xs[r][c] = (rr < Nn) ? x[rr * FIN + c] : 0.f;
  }
  __syncthreads();
  int t = threadIdx.x;
  float acc[8] = {};
  for (int kk = 0; kk < FIN; kk++) {
    float wv = w[kk * Hh + t];
#pragma unroll
    for (int r = 0; r < 8; r++) acc[r] += xs[r][kk] * wv;
  }
  float bias = b[t];
#pragma unroll
  for (int r = 0; r < 8; r++) {
    int rr = r0 + r;
    if (rr < Nn) h[rr * Hh + t] = acc[r] + bias;
  }
}

// ---- fused k,q,v,skip: 4x [N,128]@[128,128]; k/q/v stored fp16, skip fp32 ----
__global__ __launch_bounds__(128) void kqvs_kernel(const float* __restrict__ h,
    const float* __restrict__ Wk, const float* __restrict__ bk,
    const float* __restrict__ Wq, const float* __restrict__ bq,
    const float* __restrict__ Wv, const float* __restrict__ bv,
    const float* __restrict__ Ws, const float* __restrict__ bs,
    __half* __restrict__ kout, __half* __restrict__ qout,
    __half* __restrict__ vout, float* __restrict__ hnew) {
  __shared__ float hs[8][Hh];
  int r0 = blockIdx.x * 8;
  for (int i = threadIdx.x; i < 8 * Hh; i += 128) {
    int r = i >> 7, c = i & 127;
    int rr = r0 + r;
    hs[r][c] = (rr < Nn) ? h[rr * Hh + c] : 0.f;
  }
  __syncthreads();
  int t = threadIdx.x;
  float ak[8] = {}, aq[8] = {}, av[8] = {}, as_[8] = {};
  for (int kk = 0; kk < Hh; kk++) {
    float wk = Wk[kk * Hh + t];
    float wq = Wq[kk * Hh + t];
    float wv = Wv[kk * Hh + t];
    float ws = Ws[kk * Hh + t];
#pragma unroll
    for (int r = 0; r < 8; r++) {
      float hv = hs[r][kk];
      ak[r] += hv * wk;
      aq[r] += hv * wq;
      av[r] += hv * wv;
      as_[r] += hv * ws;
    }
  }
  float bkv = bk[t], bqv = bq[t], bvv = bv[t], bsv = bs[t];
#pragma unroll
  for (int r = 0; r < 8; r++) {
    int rr = r0 + r;
    if (rr < Nn) {
      kout[rr * Hh + t] = __float2half(ak[r] + bkv);
      qout[rr * Hh + t] = __float2half(aq[r] + bqv);
      vout[rr * Hh + t] = __float2half(av[r] + bvv);
      hnew[rr * Hh + t] = as_[r] + bsv;
    }
  }
}

// ---------------- CSR build ----------------
__global__ __launch_bounds__(256) void zero_kernel(int* __restrict__ p, int n) {
  int i = blockIdx.x * 256 + threadIdx.x;
  if (i < n) p[i] = 0;
}

__global__ __launch_bounds__(256) void hist_kernel(const int* __restrict__ ei_dst,
                                                   int* __restrict__ counts) {
  int e = blockIdx.x * 256 + threadIdx.x;
  if (e < Ee) atomicAdd(&counts[ei_dst[e]], 1);
}

// each block scans 1024 counts -> per-block exclusive scan + block total
__global__ __launch_bounds__(256) void scan_block_kernel(const int* __restrict__ counts,
    int* __restrict__ rowptr, int* __restrict__ bsums) {
  __shared__ int tsums[256];
  int b = blockIdx.x, t = threadIdx.x;
  int base = b * 1024 + t * 4;
  int v[4]; int s = 0;
#pragma unroll
  for (int j = 0; j < 4; j++) {
    int idx = base + j;
    v[j] = (idx < Nn) ? counts[idx] : 0;
    s += v[j];
  }
  tsums[t] = s;
  __syncthreads();
  for (int off = 1; off < 256; off <<= 1) {
    int y = (t >= off) ? tsums[t - off] : 0;
    __syncthreads();
    tsums[t] += y;
    __syncthreads();
  }
  int excl = tsums[t] - s;
#pragma unroll
  for (int j = 0; j < 4; j++) {
    int idx = base + j;
    if (idx < Nn) rowptr[idx] = excl;
    excl += v[j];
  }
  if (t == 255) bsums[b] = tsums[255];
}

__global__ __launch_bounds__(128) void scan_sums_kernel(int* __restrict__ bsums, int nb) {
  __shared__ int sh[128];
  int t = threadIdx.x;
  int v = (t < nb) ? bsums[t] : 0;
  sh[t] = v;
  __syncthreads();
  for (int off = 1; off < 128; off <<= 1) {
    int y = (t >= off) ? sh[t - off] : 0;
    __syncthreads();
    sh[t] += y;
    __syncthreads();
  }
  if (t < nb) bsums[t] = sh[t] - v;  // exclusive
}

__global__ __launch_bounds__(256) void finalize_rowptr_kernel(int* __restrict__ rowptr,
    const int* __restrict__ bsums, int* __restrict__ cursor) {
  int i = blockIdx.x * 256 + threadIdx.x;
  if (i < Nn) {
    int r = rowptr[i] + bsums[i >> 10];
    rowptr[i] = r;
    cursor[i] = r;
  }
  if (i == Nn) rowptr[Nn] = Ee;
}

// permute edge data into CSR order: src_perm (int), ea_perm (16 f32)
__global__ __launch_bounds__(256) void fill_perm_kernel(const int* __restrict__ ei_src,
    const int* __restrict__ ei_dst, const float* __restrict__ ea,
    int* __restrict__ cursor, int* __restrict__ src_perm, float* __restrict__ ea_perm) {
  int e = blockIdx.x * 256 + threadIdx.x;
  if (e < Ee) {
    int d = ei_dst[e];
    int slot = atomicAdd(&cursor[d], 1);
    src_perm[slot] = ei_src[e];
    const float4* s = (const float4*)(ea + (size_t)e * EDIMM);
    float4* dp = (float4*)(ea_perm + (size_t)slot * EDIMM);
    float4 s0 = s[0], s1 = s[1], s2 = s[2], s3 = s[3];
    dp[0] = s0; dp[1] = s1; dp[2] = s2; dp[3] = s3;
  }
}

// ---- CSR edge kernel: one wave per dst row, 4-edge batched gathers ----
__global__ __launch_bounds__(256) void edge_csr_kernel(
    const __half* __restrict__ kb, const __half* __restrict__ qb,
    const __half* __restrict__ vb, const int* __restrict__ src_perm,
    const float* __restrict__ ea_perm, const int* __restrict__ rowptr,
    const float* __restrict__ We_l, const float* __restrict__ be_l,
    const float* __restrict__ ln_g_l, const float* __restrict__ ln_b_l,
    float* __restrict__ hbuf) {
  int wave = threadIdx.x >> 6;
  int lane = threadIdx.x & 63;
  int row = blockIdx.x * 4 + wave;   // grid 25000*4 = 100000 exactly
  int c0 = lane * 2;

  float w0[EDIMM], w1[EDIMM];
#pragma unroll
  for (int d = 0; d < EDIMM; d++) {
    float2 wv = *(const float2*)(We_l + d * Hh + c0);
    w0[d] = wv.x; w1[d] = wv.y;
  }
  float2 bev = *(const float2*)(be_l + c0);

  __half2 kh = *(const __half2*)(kb + (size_t)row * Hh + c0);
  float k0 = __half2float(kh.x), k1 = __half2float(kh.y);

  float agg0 = 0.f, agg1 = 0.f;
  int beg = rowptr[row], end = rowptr[row + 1];

  auto edge_math = [&](int eslot, float q0, float q1, float v0, float v1) {
    const float4* ea4 = (const float4*)(ea_perm + (size_t)eslot * EDIMM);
    float4 a0 = ea4[0], a1 = ea4[1], a2 = ea4[2], a3 = ea4[3];
    float emb0 = bev.x, emb1 = bev.y;
    emb0 += a0.x*w0[0] + a0.y*w0[1] + a0.z*w0[2] + a0.w*w0[3];
    emb1 += a0.x*w1[0] + a0.y*w1[1] + a0.z*w1[2] + a0.w*w1[3];
    emb0 += a1.x*w0[4] + a1.y*w0[5] + a1.z*w0[6] + a1.w*w0[7];
    emb1 += a1.x*w1[4] + a1.y*w1[5] + a1.z*w1[6] + a1.w*w1[7];
    emb0 += a2.x*w0[8] + a2.y*w0[9] + a2.z*w0[10] + a2.w*w0[11];
    emb1 += a2.x*w1[8] + a2.y*w1[9] + a2.z*w1[10] + a2.w*w1[11];
    emb0 += a3.x*w0[12] + a3.y*w0[13] + a3.z*w0[14] + a3.w*w0[15];
    emb1 += a3.x*w1[12] + a3.y*w1[13] + a3.z*w1[14] + a3.w*w1[15];
    float g0 = k0 + emb0 + q0;
    float g1 = k1 + emb1 + q1;
    g0 = 1.f / (1.f + __expf(-g0));
    g1 = 1.f / (1.f + __expf(-g1));
    agg0 += g0 * v0;
    agg1 += g1 * v1;
  };

  int e = beg;
  for (; e + 4 <= end; e += 4) {
    int4 s4 = *(const int4*)(src_perm + e);
    // issue all 8 gathers up front -> 4x MLP inside the wave
    __half2 q0 = *(const __half2*)(qb + (size_t)s4.x * Hh + c0);
    __half2 v0 = *(const __half2*)(vb + (size_t)s4.x * Hh + c0);
    __half2 q1 = *(const __half2*)(qb + (size_t)s4.y * Hh + c0);
    __half2 v1 = *(const __half2*)(vb + (size_t)s4.y * Hh + c0);
    __half2 q2 = *(const __half2*)(qb + (size_t)s4.z * Hh + c0);
    __half2 v2 = *(const __half2*)(vb + (size_t)s4.z * Hh + c0);
    __half2 q3 = *(const __half2*)(qb + (size_t)s4.w * Hh + c0);
    __half2 v3 = *(const __half2*)(vb + (size_t)s4.w * Hh + c0);
    edge_math(e + 0, __half2float(q0.x), __half2float(q0.y), __half2float(v0.x), __half2float(v0.y));
    edge_math(e + 1, __half2float(q1.x), __half2float(q1.y), __half2float(v1.x), __half2float(v1.y));
    edge_math(e + 2, __half2float(q2.x), __half2float(q2.y), __half2float(v2.x), __half2float(v2.y));
    edge_math(e + 3, __half2float(q3.x), __half2float(q3.y), __half2float(v3.x), __half2float(v3.y));
  }
  for (; e < end; e++) {
    int src = src_perm[e];
    __half2 qh = *(const __half2*)(qb + (size_t)src * Hh + c0);
    __half2 vh = *(const __half2*)(vb + (size_t)src * Hh + c0);
    edge_math(e, __half2float(qh.x), __half2float(qh.y), __half2float(vh.x), __half2float(vh.y));
  }

  // skip + LayerNorm + GELU (wave owns full row: 2 channels/lane)
  float2 hv = *(float2*)(hbuf + (size_t)row * Hh + c0);
  float y0 = hv.x + agg0, y1 = hv.y + agg1;
  float s = y0 + y1;
#pragma unroll
  for (int off = 32; off; off >>= 1) s += __shfl_xor(s, off);
  float mu = s * (1.f / 128.f);
  float d0 = y0 - mu, d1 = y1 - mu;
  float vv = d0 * d0 + d1 * d1;
#pragma unroll
  for (int off = 32; off; off >>= 1) vv += __shfl_xor(vv, off);
  float rstd = rsqrtf(vv * (1.f / 128.f) + 1e-5f);
  float2 lg = *(const float2*)(ln_g_l + c0);
  float2 lb = *(const float2*)(ln_b_l + c0);
  float o0 = d0 * rstd * lg.x + lb.x;
  float o1 = d1 * rstd * lg.y + lb.y;
  o0 = 0.5f * o0 * (1.f + erff(o0 * 0.70710678118654752f));
  o1 = 0.5f * o1 * (1.f + erff(o1 * 0.70710678118654752f));
  *(float2*)(hbuf + (size_t)row * Hh + c0) = make_float2(o0, o1);
}

// ---- out_proj: out = h @ out_w  [N,128]@[128,64] ----
__global__ __launch_bounds__(64) void out_proj_kernel(const float* __restrict__ h,
    const float* __restrict__ w, float* __restrict__ out) {
  __shared__ float hs[16][Hh];
  int r0 = blockIdx.x * 16;
  for (int i = threadIdx.x; i < 16 * Hh; i += 64) {
    int r = i >> 7, c = i & 127;
    int rr = r0 + r;
    hs[r][c] = (rr < Nn) ? h[rr * Hh + c] : 0.f;
  }
  __syncthreads();
  int t = threadIdx.x;
  float acc[16] = {};
  for (int kk = 0; kk < Hh; kk++) {
    float wv = w[kk * NOUT + t];
#pragma unroll
    for (int r = 0; r < 16; r++) acc[r] += hs[r][kk] * wv;
  }
#pragma unroll
  for (int r = 0; r < 16; r++) {
    int rr = r0 + r;
    if (rr < Nn) out[rr * NOUT + t] = acc[r];
  }
}

extern "C" void kernel_launch(void* const* d_in, const int* in_sizes, int n_in,
                              void* d_out, int out_size, void* d_ws, size_t ws_size,
                              hipStream_t stream) {
  const float* x    = (const float*)d_in[0];
  const int*   ei   = (const int*)d_in[1];
  const float* ea   = (const float*)d_in[2];
  const float* in_w = (const float*)d_in[3];
  const float* in_b = (const float*)d_in[4];
  const float* Wk   = (const float*)d_in[5];
  const float* bk   = (const float*)d_in[6];
  const float* Wq   = (const float*)d_in[7];
  const float* bq   = (const float*)d_in[8];
  const float* Wv   = (const float*)d_in[9];
  const float* bv   = (const float*)d_in[10];
  const float* We   = (const float*)d_in[11];
  const float* be   = (const float*)d_in[12];
  const float* Ws   = (const float*)d_in[13];
  const float* bs   = (const float*)d_in[14];
  const float* ln_g = (const float*)d_in[15];
  const float* ln_b = (const float*)d_in[16];
  const float* out_w = (const float*)d_in[17];
  float* out = (float*)d_out;

  const int* ei_src = ei;
  const int* ei_dst = ei + Ee;

  size_t NH = (size_t)Nn * Hh;
  char* wsp = (char*)d_ws;
  float*  hA = (float*)wsp;           wsp += NH * 4;
  float*  hB = (float*)wsp;           wsp += NH * 4;
  __half* kb = (__half*)wsp;          wsp += NH * 2;
  __half* qb = (__half*)wsp;          wsp += NH * 2;
  __half* vb = (__half*)wsp;          wsp += NH * 2;
  int* rowptr = (int*)wsp;            wsp += (Nn + 1) * 4;
  int* cursor = (int*)wsp;            wsp += Nn * 4;
  int* bsums  = (int*)wsp;            wsp += 128 * 4;
  int* src_perm = (int*)wsp;          wsp += (size_t)Ee * 4;
  float* ea_perm = (float*)wsp;       wsp += (size_t)Ee * EDIMM * 4;

  const int NB_SCAN = (Nn + 1023) / 1024;   // 98

  // CSR build + edge permute (edge_index shared by all layers)
  zero_kernel<<<(Nn + 255) / 256, 256, 0, stream>>>(cursor, Nn);
  hist_kernel<<<(Ee + 255) / 256, 256, 0, stream>>>(ei_dst, cursor);
  scan_block_kernel<<<NB_SCAN, 256, 0, stream>>>(cursor, rowptr, bsums);
  scan_sums_kernel<<<1, 128, 0, stream>>>(bsums, NB_SCAN);
  finalize_rowptr_kernel<<<(Nn + 1 + 255) / 256, 256, 0, stream>>>(rowptr, bsums, cursor);
  fill_perm_kernel<<<(Ee + 255) / 256, 256, 0, stream>>>(ei_src, ei_dst, ea, cursor,
                                                         src_perm, ea_perm);

  in_proj_kernel<<<(Nn + 7) / 8, 128, 0, stream>>>(x, in_w, in_b, hA);

  float* h  = hA;
  float* hn = hB;
  for (int l = 0; l < NL; l++) {
    kqvs_kernel<<<(Nn + 7) / 8, 128, 0, stream>>>(h,
        Wk + l * Hh * Hh, bk + l * Hh,
        Wq + l * Hh * Hh, bq + l * Hh,
        Wv + l * Hh * Hh, bv + l * Hh,
        Ws + l * Hh * Hh, bs + l * Hh,
        kb, qb, vb, hn);
    edge_csr_kernel<<<Nn / 4, 256, 0, stream>>>(kb, qb, vb, src_perm, ea_perm,
        rowptr, We + l * EDIMM * Hh, be + l * Hh,
        ln_g + l * Hh, ln_b + l * Hh, hn);
    float* tmp = h; h = hn; hn = tmp;
  }

  out_proj_kernel<<<(Nn + 15) / 16, 64, 0, stream>>>(h, out_w, out);
}

// Round 4
// 2354.919 us; speedup vs baseline: 1.0584x; 1.0584x over previous
//
#include <hip/hip_runtime.h>
#include <hip/hip_fp16.h>
#include <cmath>

#define Nn   100000
#define Ee   1600000
#define FIN  256
#define Hh   128
#define EDIMM 16
#define NL   3
#define NOUT 64

static __device__ __forceinline__ __half2 u2h2(unsigned int u) {
  union { unsigned int u; __half2 h; } c; c.u = u; return c.h;
}
static __device__ __forceinline__ unsigned int h22u(__half2 h) {
  union { unsigned int u; __half2 h; } c; c.h = h; return c.u;
}

// ---------------- in_proj: h = x @ in_w + in_b  [N,256]@[256,128] ----------------
__global__ __launch_bounds__(128) void in_proj_kernel(const float* __restrict__ x,
    const float* __restrict__ w, const float* __restrict__ b, float* __restrict__ h) {
  __shared__ float xs[8][FIN];
  int r0 = blockIdx.x * 8;
  for (int i = threadIdx.x; i < 8 * FIN; i += 128) {
    int r = i >> 8, c = i & (FIN - 1);
    int rr = r0 + r;
    xs[r][c] = (rr < Nn) ? x[rr * FIN + c] : 0.f;
  }
  __syncthreads();
  int t = threadIdx.x;
  float acc[8] = {};
  for (int kk = 0; kk < FIN; kk++) {
    float wv = w[kk * Hh + t];
#pragma unroll
    for (int r = 0; r < 8; r++) acc[r] += xs[r][kk] * wv;
  }
  float bias = b[t];
#pragma unroll
  for (int r = 0; r < 8; r++) {
    int rr = r0 + r;
    if (rr < Nn) h[rr * Hh + t] = acc[r] + bias;
  }
}

// ---- fused k,q,v,skip: 4x [N,128]@[128,128]; k fp16, q/v interleaved fp16, skip fp32 ----
__global__ __launch_bounds__(128) void kqvs_kernel(const float* __restrict__ h,
    const float* __restrict__ Wk, const float* __restrict__ bk,
    const float* __restrict__ Wq, const float* __restrict__ bq,
    const float* __restrict__ Wv, const float* __restrict__ bv,
    const float* __restrict__ Ws, const float* __restrict__ bs,
    __half* __restrict__ kout, __half* __restrict__ qvb, float* __restrict__ hnew) {
  __shared__ float hs[8][Hh];
  int r0 = blockIdx.x * 8;
  for (int i = threadIdx.x; i < 8 * Hh; i += 128) {
    int r = i >> 7, c = i & 127;
    int rr = r0 + r;
    hs[r][c] = (rr < Nn) ? h[rr * Hh + c] : 0.f;
  }
  __syncthreads();
  int t = threadIdx.x;
  float ak[8] = {}, aq[8] = {}, av[8] = {}, as_[8] = {};
  for (int kk = 0; kk < Hh; kk++) {
    float wk = Wk[kk * Hh + t];
    float wq = Wq[kk * Hh + t];
    float wv = Wv[kk * Hh + t];
    float ws = Ws[kk * Hh + t];
#pragma unroll
    for (int r = 0; r < 8; r++) {
      float hv = hs[r][kk];
      ak[r] += hv * wk;
      aq[r] += hv * wq;
      av[r] += hv * wv;
      as_[r] += hv * ws;
    }
  }
  float bkv = bk[t], bqv = bq[t], bvv = bv[t], bsv = bs[t];
#pragma unroll
  for (int r = 0; r < 8; r++) {
    int rr = r0 + r;
    if (rr < Nn) {
      kout[rr * Hh + t] = __float2half(ak[r] + bkv);
      qvb[(size_t)rr * 256 + t]       = __float2half(aq[r] + bqv);
      qvb[(size_t)rr * 256 + 128 + t] = __float2half(av[r] + bvv);
      hnew[rr * Hh + t] = as_[r] + bsv;
    }
  }
}

// ---------------- CSR build ----------------
__global__ __launch_bounds__(256) void zero_kernel(int* __restrict__ p, int n) {
  int i = blockIdx.x * 256 + threadIdx.x;
  if (i < n) p[i] = 0;
}

__global__ __launch_bounds__(256) void hist_kernel(const int* __restrict__ ei_dst,
                                                   int* __restrict__ counts) {
  int e = blockIdx.x * 256 + threadIdx.x;
  if (e < Ee) atomicAdd(&counts[ei_dst[e]], 1);
}

__global__ __launch_bounds__(256) void scan_block_kernel(const int* __restrict__ counts,
    int* __restrict__ rowptr, int* __restrict__ bsums) {
  __shared__ int tsums[256];
  int b = blockIdx.x, t = threadIdx.x;
  int base = b * 1024 + t * 4;
  int v[4]; int s = 0;
#pragma unroll
  for (int j = 0; j < 4; j++) {
    int idx = base + j;
    v[j] = (idx < Nn) ? counts[idx] : 0;
    s += v[j];
  }
  tsums[t] = s;
  __syncthreads();
  for (int off = 1; off < 256; off <<= 1) {
    int y = (t >= off) ? tsums[t - off] : 0;
    __syncthreads();
    tsums[t] += y;
    __syncthreads();
  }
  int excl = tsums[t] - s;
#pragma unroll
  for (int j = 0; j < 4; j++) {
    int idx = base + j;
    if (idx < Nn) rowptr[idx] = excl;
    excl += v[j];
  }
  if (t == 255) bsums[b] = tsums[255];
}

__global__ __launch_bounds__(128) void scan_sums_kernel(int* __restrict__ bsums, int nb) {
  __shared__ int sh[128];
  int t = threadIdx.x;
  int v = (t < nb) ? bsums[t] : 0;
  sh[t] = v;
  __syncthreads();
  for (int off = 1; off < 128; off <<= 1) {
    int y = (t >= off) ? sh[t - off] : 0;
    __syncthreads();
    sh[t] += y;
    __syncthreads();
  }
  if (t < nb) bsums[t] = sh[t] - v;
}

__global__ __launch_bounds__(256) void finalize_rowptr_kernel(int* __restrict__ rowptr,
    const int* __restrict__ bsums, int* __restrict__ cursor) {
  int i = blockIdx.x * 256 + threadIdx.x;
  if (i < Nn) {
    int r = rowptr[i] + bsums[i >> 10];
    rowptr[i] = r;
    cursor[i] = r;
  }
  if (i == Nn) rowptr[Nn] = Ee;
}

// permute: src_perm (int), ea_perm = pre-broadcast half2 (16 uints/edge, 64 B)
__global__ __launch_bounds__(256) void fill_perm_kernel(const int* __restrict__ ei_src,
    const int* __restrict__ ei_dst, const float* __restrict__ ea,
    int* __restrict__ cursor, int* __restrict__ src_perm,
    unsigned int* __restrict__ ea_perm) {
  int e = blockIdx.x * 256 + threadIdx.x;
  if (e < Ee) {
    int d = ei_dst[e];
    int slot = atomicAdd(&cursor[d], 1);
    src_perm[slot] = ei_src[e];
    const float4* s = (const float4*)(ea + (size_t)e * EDIMM);
    float4 f[4] = { s[0], s[1], s[2], s[3] };
    unsigned int u[16];
#pragma unroll
    for (int j = 0; j < 4; j++) {
      u[j*4+0] = h22u(__half2half2(__float2half(f[j].x)));
      u[j*4+1] = h22u(__half2half2(__float2half(f[j].y)));
      u[j*4+2] = h22u(__half2half2(__float2half(f[j].z)));
      u[j*4+3] = h22u(__half2half2(__float2half(f[j].w)));
    }
    uint4* dp = (uint4*)(ea_perm + (size_t)slot * EDIMM);
#pragma unroll
    for (int j = 0; j < 4; j++)
      dp[j] = make_uint4(u[j*4+0], u[j*4+1], u[j*4+2], u[j*4+3]);
  }
}

// ---- CSR edge kernel: one wave per dst row, packed-fp16 math ----
__global__ __launch_bounds__(256) void edge_csr_kernel(
    const __half* __restrict__ kb, const __half* __restrict__ qvb,
    const int* __restrict__ src_perm, const unsigned int* __restrict__ ea_perm,
    const int* __restrict__ rowptr,
    const float* __restrict__ We_l, const float* __restrict__ be_l,
    const float* __restrict__ ln_g_l, const float* __restrict__ ln_b_l,
    float* __restrict__ hbuf) {
  int wave = threadIdx.x >> 6;
  int lane = threadIdx.x & 63;
  int row = blockIdx.x * 4 + wave;   // grid 25000*4 = 100000 exactly
  int c0 = lane * 2;

  // We columns (2 channels) packed to half2 registers
  __half2 wpk[EDIMM];
#pragma unroll
  for (int d = 0; d < EDIMM; d++) {
    float2 wv = *(const float2*)(We_l + d * Hh + c0);
    wpk[d] = __floats2half2_rn(wv.x, wv.y);
  }
  float2 bef = *(const float2*)(be_l + c0);
  __half2 bev = __floats2half2_rn(bef.x, bef.y);

  __half2 kpk = *(const __half2*)(kb + (size_t)row * Hh + c0);

  float agg0 = 0.f, agg1 = 0.f;
  int beg = rowptr[row], end = rowptr[row + 1];

  auto edge_math = [&](int eslot, __half2 qh, __half2 vh) {
    const uint4* ea4 = (const uint4*)(ea_perm + (size_t)eslot * EDIMM);
    uint4 a0 = ea4[0], a1 = ea4[1], a2 = ea4[2], a3 = ea4[3];
    __half2 acc = bev;
    acc = __hfma2(u2h2(a0.x), wpk[0],  acc);
    acc = __hfma2(u2h2(a0.y), wpk[1],  acc);
    acc = __hfma2(u2h2(a0.z), wpk[2],  acc);
    acc = __hfma2(u2h2(a0.w), wpk[3],  acc);
    acc = __hfma2(u2h2(a1.x), wpk[4],  acc);
    acc = __hfma2(u2h2(a1.y), wpk[5],  acc);
    acc = __hfma2(u2h2(a1.z), wpk[6],  acc);
    acc = __hfma2(u2h2(a1.w), wpk[7],  acc);
    acc = __hfma2(u2h2(a2.x), wpk[8],  acc);
    acc = __hfma2(u2h2(a2.y), wpk[9],  acc);
    acc = __hfma2(u2h2(a2.z), wpk[10], acc);
    acc = __hfma2(u2h2(a2.w), wpk[11], acc);
    acc = __hfma2(u2h2(a3.x), wpk[12], acc);
    acc = __hfma2(u2h2(a3.y), wpk[13], acc);
    acc = __hfma2(u2h2(a3.z), wpk[14], acc);
    acc = __hfma2(u2h2(a3.w), wpk[15], acc);
    __half2 pre = __hadd2(__hadd2(kpk, qh), acc);
    float p0 = __half2float(__low2half(pre));
    float p1 = __half2float(__high2half(pre));
    float g0 = 1.f / (1.f + __expf(-p0));
    float g1 = 1.f / (1.f + __expf(-p1));
    agg0 += g0 * __half2float(__low2half(vh));
    agg1 += g1 * __half2float(__high2half(vh));
  };

  int e = beg;
  for (; e + 4 <= end; e += 4) {
    int4 s4 = *(const int4*)(src_perm + e);
    const __half* p0 = qvb + (size_t)s4.x * 256 + c0;
    const __half* p1 = qvb + (size_t)s4.y * 256 + c0;
    const __half* p2 = qvb + (size_t)s4.z * 256 + c0;
    const __half* p3 = qvb + (size_t)s4.w * 256 + c0;
    __half2 q0 = *(const __half2*)p0, v0 = *(const __half2*)(p0 + 128);
    __half2 q1 = *(const __half2*)p1, v1 = *(const __half2*)(p1 + 128);
    __half2 q2 = *(const __half2*)p2, v2 = *(const __half2*)(p2 + 128);
    __half2 q3 = *(const __half2*)p3, v3 = *(const __half2*)(p3 + 128);
    edge_math(e + 0, q0, v0);
    edge_math(e + 1, q1, v1);
    edge_math(e + 2, q2, v2);
    edge_math(e + 3, q3, v3);
  }
  for (; e < end; e++) {
    int src = src_perm[e];
    const __half* p = qvb + (size_t)src * 256 + c0;
    edge_math(e, *(const __half2*)p, *(const __half2*)(p + 128));
  }

  // skip + LayerNorm + GELU (wave owns full row: 2 channels/lane)
  float2 hv = *(float2*)(hbuf + (size_t)row * Hh + c0);
  float y0 = hv.x + agg0, y1 = hv.y + agg1;
  float s = y0 + y1;
#pragma unroll
  for (int off = 32; off; off >>= 1) s += __shfl_xor(s, off);
  float mu = s * (1.f / 128.f);
  float d0 = y0 - mu, d1 = y1 - mu;
  float vv = d0 * d0 + d1 * d1;
#pragma unroll
  for (int off = 32; off; off >>= 1) vv += __shfl_xor(vv, off);
  float rstd = rsqrtf(vv * (1.f / 128.f) + 1e-5f);
  float2 lg = *(const float2*)(ln_g_l + c0);
  float2 lb = *(const float2*)(ln_b_l + c0);
  float o0 = d0 * rstd * lg.x + lb.x;
  float o1 = d1 * rstd * lg.y + lb.y;
  o0 = 0.5f * o0 * (1.f + erff(o0 * 0.70710678118654752f));
  o1 = 0.5f * o1 * (1.f + erff(o1 * 0.70710678118654752f));
  *(float2*)(hbuf + (size_t)row * Hh + c0) = make_float2(o0, o1);
}

// ---- out_proj: out = h @ out_w  [N,128]@[128,64] ----
__global__ __launch_bounds__(64) void out_proj_kernel(const float* __restrict__ h,
    const float* __restrict__ w, float* __restrict__ out) {
  __shared__ float hs[16][Hh];
  int r0 = blockIdx.x * 16;
  for (int i = threadIdx.x; i < 16 * Hh; i += 64) {
    int r = i >> 7, c = i & 127;
    int rr = r0 + r;
    hs[r][c] = (rr < Nn) ? h[rr * Hh + c] : 0.f;
  }
  __syncthreads();
  int t = threadIdx.x;
  float acc[16] = {};
  for (int kk = 0; kk < Hh; kk++) {
    float wv = w[kk * NOUT + t];
#pragma unroll
    for (int r = 0; r < 16; r++) acc[r] += hs[r][kk] * wv;
  }
#pragma unroll
  for (int r = 0; r < 16; r++) {
    int rr = r0 + r;
    if (rr < Nn) out[rr * NOUT + t] = acc[r];
  }
}

extern "C" void kernel_launch(void* const* d_in, const int* in_sizes, int n_in,
                              void* d_out, int out_size, void* d_ws, size_t ws_size,
                              hipStream_t stream) {
  const float* x    = (const float*)d_in[0];
  const int*   ei   = (const int*)d_in[1];
  const float* ea   = (const float*)d_in[2];
  const float* in_w = (const float*)d_in[3];
  const float* in_b = (const float*)d_in[4];
  const float* Wk   = (const float*)d_in[5];
  const float* bk   = (const float*)d_in[6];
  const float* Wq   = (const float*)d_in[7];
  const float* bq   = (const float*)d_in[8];
  const float* Wv   = (const float*)d_in[9];
  const float* bv   = (const float*)d_in[10];
  const float* We   = (const float*)d_in[11];
  const float* be   = (const float*)d_in[12];
  const float* Ws   = (const float*)d_in[13];
  const float* bs   = (const float*)d_in[14];
  const float* ln_g = (const float*)d_in[15];
  const float* ln_b = (const float*)d_in[16];
  const float* out_w = (const float*)d_in[17];
  float* out = (float*)d_out;

  const int* ei_src = ei;
  const int* ei_dst = ei + Ee;

  size_t NH = (size_t)Nn * Hh;
  char* wsp = (char*)d_ws;
  float*  hA = (float*)wsp;           wsp += NH * 4;
  float*  hB = (float*)wsp;           wsp += NH * 4;
  __half* kb = (__half*)wsp;          wsp += NH * 2;
  __half* qvb = (__half*)wsp;         wsp += NH * 2 * 2;   // [N,256] interleaved q|v
  int* rowptr = (int*)wsp;            wsp += (Nn + 1) * 4;
  int* cursor = (int*)wsp;            wsp += Nn * 4;
  int* bsums  = (int*)wsp;            wsp += 128 * 4;
  int* src_perm = (int*)wsp;          wsp += (size_t)Ee * 4;
  unsigned int* ea_perm = (unsigned int*)wsp; wsp += (size_t)Ee * EDIMM * 4;

  const int NB_SCAN = (Nn + 1023) / 1024;   // 98

  zero_kernel<<<(Nn + 255) / 256, 256, 0, stream>>>(cursor, Nn);
  hist_kernel<<<(Ee + 255) / 256, 256, 0, stream>>>(ei_dst, cursor);
  scan_block_kernel<<<NB_SCAN, 256, 0, stream>>>(cursor, rowptr, bsums);
  scan_sums_kernel<<<1, 128, 0, stream>>>(bsums, NB_SCAN);
  finalize_rowptr_kernel<<<(Nn + 1 + 255) / 256, 256, 0, stream>>>(rowptr, bsums, cursor);
  fill_perm_kernel<<<(Ee + 255) / 256, 256, 0, stream>>>(ei_src, ei_dst, ea, cursor,
                                                         src_perm, ea_perm);

  in_proj_kernel<<<(Nn + 7) / 8, 128, 0, stream>>>(x, in_w, in_b, hA);

  float* h  = hA;
  float* hn = hB;
  for (int l = 0; l < NL; l++) {
    kqvs_kernel<<<(Nn + 7) / 8, 128, 0, stream>>>(h,
        Wk + l * Hh * Hh, bk + l * Hh,
        Wq + l * Hh * Hh, bq + l * Hh,
        Wv + l * Hh * Hh, bv + l * Hh,
        Ws + l * Hh * Hh, bs + l * Hh,
        kb, qvb, hn);
    edge_csr_kernel<<<Nn / 4, 256, 0, stream>>>(kb, qvb, src_perm, ea_perm,
        rowptr, We + l * EDIMM * Hh, be + l * Hh,
        ln_g + l * Hh, ln_b + l * Hh, hn);
    float* tmp = h; h = hn; hn = tmp;
  }

  out_proj_kernel<<<(Nn + 15) / 16, 64, 0, stream>>>(h, out_w, out);
}